// Round 1
// baseline (277.153 us; speedup 1.0000x reference)
//
#include <hip/hip_runtime.h>
#include <hip/hip_bf16.h>

#define B_ 8
#define N_ 2048
#define FIN 256
#define FOUT 64
#define BN_ (B_ * N_)
#define SEG 8
#define KSEG (N_ / SEG)        // 256
#define LDJ (KSEG + 8)         // 264 -> byte stride 528 = 33*16B, conflict-free b128 reads
#define NEG_INF_F (-9.0e15f)

typedef unsigned short ushort_t;
typedef __attribute__((ext_vector_type(8))) __bf16 bf16x8;
typedef __attribute__((ext_vector_type(4))) float f32x4;

union U4B8 { uint4 u; bf16x8 b; };

__device__ __forceinline__ float lrelu(float x) { return fmaxf(x, 0.2f * x); }

// ---------------- K1: Wh = h @ W ; e_src/e_dst ; WhT stored bf16 transposed ----------------
// block = 256 thr = 4 waves; each wave: 4 consecutive rows, lane = output col c.
__global__ __launch_bounds__(256) void k1_proj(
    const float* __restrict__ h, const float* __restrict__ W,
    const float* __restrict__ a, ushort_t* __restrict__ WhTB,
    float* __restrict__ e_src, float* __restrict__ e_dst)
{
    const int t = threadIdx.x;
    const int lane = t & 63;
    const int w = t >> 6;
    const int gr = blockIdx.x * 16 + w * 4;  // global row (b*N+i), 4 rows per wave
    const int c = lane;
    const float* hrow = h + (size_t)gr * FIN;
    float v0 = 0.f, v1 = 0.f, v2 = 0.f, v3 = 0.f;
    for (int k = 0; k < FIN; k += 4) {
        const float4 h0 = *(const float4*)(hrow + k);
        const float4 h1 = *(const float4*)(hrow + FIN + k);
        const float4 h2 = *(const float4*)(hrow + 2 * FIN + k);
        const float4 h3 = *(const float4*)(hrow + 3 * FIN + k);
        const float w0 = W[(k + 0) * FOUT + c];
        const float w1 = W[(k + 1) * FOUT + c];
        const float w2 = W[(k + 2) * FOUT + c];
        const float w3 = W[(k + 3) * FOUT + c];
        v0 += h0.x * w0 + h0.y * w1 + h0.z * w2 + h0.w * w3;
        v1 += h1.x * w0 + h1.y * w1 + h1.z * w2 + h1.w * w3;
        v2 += h2.x * w0 + h2.y * w1 + h2.z * w2 + h2.w * w3;
        v3 += h3.x * w0 + h3.y * w1 + h3.z * w2 + h3.w * w3;
    }
    // e_src/e_dst wave reductions over c
    const float a1c = a[c], a2c = a[FOUT + c];
    float s10 = v0 * a1c, s11 = v1 * a1c, s12 = v2 * a1c, s13 = v3 * a1c;
    float s20 = v0 * a2c, s21 = v1 * a2c, s22 = v2 * a2c, s23 = v3 * a2c;
    for (int off = 32; off; off >>= 1) {
        s10 += __shfl_xor(s10, off); s11 += __shfl_xor(s11, off);
        s12 += __shfl_xor(s12, off); s13 += __shfl_xor(s13, off);
        s20 += __shfl_xor(s20, off); s21 += __shfl_xor(s21, off);
        s22 += __shfl_xor(s22, off); s23 += __shfl_xor(s23, off);
    }
    if (lane == 0) {
        *(float4*)(e_src + gr) = make_float4(s10, s11, s12, s13);
        *(float4*)(e_dst + gr) = make_float4(s20, s21, s22, s23);
    }
    // WhT[b][c][i] bf16 (transposed so K3 stages K-contiguous runs)
    const int b = gr >> 11, i = gr & (N_ - 1);
    ushort4 us;
    us.x = __builtin_bit_cast(unsigned short, (__bf16)v0);
    us.y = __builtin_bit_cast(unsigned short, (__bf16)v1);
    us.z = __builtin_bit_cast(unsigned short, (__bf16)v2);
    us.w = __builtin_bit_cast(unsigned short, (__bf16)v3);
    *(ushort4*)(WhTB + (size_t)(b * FOUT + c) * N_ + i) = us;
}

// ---------------- K3: unnormalized PV via MFMA + row-sum atomics ----------------
// grid (128, SEG). block = 4 waves; wave tile = 32 rows x 64 cols, K-segment 256.
// P~[i][j] = adj ? exp(leaky(e_src[i]+e_dst[j])) : 0  (masked exp underflows to exactly 0).
__global__ __launch_bounds__(256) void k3_attn(
    const int* __restrict__ adj, const ushort_t* __restrict__ WhTB,
    const float* __restrict__ e_src, const float* __restrict__ e_dst,
    float* __restrict__ s_buf, float* __restrict__ partial)
{
    __shared__ ushort_t WhT[FOUT * LDJ];   // 33792 B
    __shared__ float edl[KSEG];            // 1024 B
    const int t = threadIdx.x;
    const int lane = t & 63, wid = t >> 6;
    const int b = blockIdx.x >> 4, tg = blockIdx.x & 15;
    const int seg = blockIdx.y;
    const int jseg = seg * KSEG;

    // stage Wh^T segment: 64 c x 256 j bf16 (32 KB), coalesced 16B per thread
    #pragma unroll
    for (int it = 0; it < 8; ++it) {
        const int chunk = it * 256 + t;
        const int cc = chunk >> 5, j8 = (chunk & 31) * 8;
        *(uint4*)(&WhT[cc * LDJ + j8]) =
            *(const uint4*)(WhTB + (size_t)(b * FOUT + cc) * N_ + jseg + j8);
    }
    if (t < 64) *(float4*)(&edl[t * 4]) = *(const float4*)(e_dst + b * N_ + jseg + t * 4);
    __syncthreads();

    const int l15 = lane & 15, g = lane >> 4;   // MFMA lane decomposition
    const int i0 = (tg * 4 + wid) * 32;         // wave's row base within batch
    const int rlo = b * N_ + i0 + l15;
    const int rhi = rlo + 16;
    const int* adj_lo = adj + (size_t)rlo * N_ + jseg;
    const int* adj_hi = adj + (size_t)rhi * N_ + jseg;
    const float es_lo = e_src[rlo], es_hi = e_src[rhi];

    f32x4 acc[2][4];
    #pragma unroll
    for (int m = 0; m < 2; ++m)
        #pragma unroll
        for (int n = 0; n < 4; ++n)
            #pragma unroll
            for (int r = 0; r < 4; ++r) acc[m][n][r] = 0.f;

    float slo = 0.f, shi = 0.f;

    for (int kc = 0; kc < KSEG; kc += 32) {
        const int jl = kc + g * 8;  // this lane's 8-k window (A/B frag is K-contiguous)
        const int4 alo0 = *(const int4*)(adj_lo + jl);
        const int4 alo1 = *(const int4*)(adj_lo + jl + 4);
        const int4 ahi0 = *(const int4*)(adj_hi + jl);
        const int4 ahi1 = *(const int4*)(adj_hi + jl + 4);
        const float4 ed0 = *(const float4*)(&edl[jl]);
        const float4 ed1 = *(const float4*)(&edl[jl + 4]);
        const float ev[8] = {ed0.x, ed0.y, ed0.z, ed0.w, ed1.x, ed1.y, ed1.z, ed1.w};
        const int alo[8] = {alo0.x, alo0.y, alo0.z, alo0.w, alo1.x, alo1.y, alo1.z, alo1.w};
        const int ahi[8] = {ahi0.x, ahi0.y, ahi0.z, ahi0.w, ahi1.x, ahi1.y, ahi1.z, ahi1.w};
        bf16x8 aflo, afhi;
        #pragma unroll
        for (int u = 0; u < 8; ++u) {
            float e0 = lrelu(es_lo + ev[u]);
            e0 = alo[u] > 0 ? e0 : NEG_INF_F;
            const float p0 = __expf(e0);
            slo += p0;
            aflo[u] = (__bf16)p0;
            float e1 = lrelu(es_hi + ev[u]);
            e1 = ahi[u] > 0 ? e1 : NEG_INF_F;
            const float p1 = __expf(e1);
            shi += p1;
            afhi[u] = (__bf16)p1;
        }
        #pragma unroll
        for (int n = 0; n < 4; ++n) {
            U4B8 bfr;
            bfr.u = *(const uint4*)(&WhT[(n * 16 + l15) * LDJ + jl]);
            acc[0][n] = __builtin_amdgcn_mfma_f32_16x16x32_bf16(aflo, bfr.b, acc[0][n], 0, 0, 0);
            acc[1][n] = __builtin_amdgcn_mfma_f32_16x16x32_bf16(afhi, bfr.b, acc[1][n], 0, 0, 0);
        }
    }
    // segment row-sums -> global s
    slo += __shfl_xor(slo, 16); slo += __shfl_xor(slo, 32);
    shi += __shfl_xor(shi, 16); shi += __shfl_xor(shi, 32);
    if (lane < 16) {
        atomicAdd(&s_buf[b * N_ + i0 + lane], slo);
        atomicAdd(&s_buf[b * N_ + i0 + 16 + lane], shi);
    }
    // store partials: C layout col=l15 (n*16+), row=g*4+r (m*16+)
    const size_t base = ((size_t)seg * BN_ + b * N_ + i0) * FOUT;
    #pragma unroll
    for (int m = 0; m < 2; ++m)
        #pragma unroll
        for (int n = 0; n < 4; ++n)
            #pragma unroll
            for (int r = 0; r < 4; ++r) {
                const int row = m * 16 + g * 4 + r;
                const int col = n * 16 + l15;
                partial[base + (size_t)row * FOUT + col] = acc[m][n][r];
            }
}

// ---------------- K4: combine segments, normalize, ELU ----------------
__global__ __launch_bounds__(256) void k4_out(
    const float* __restrict__ partial, const float* __restrict__ s_buf,
    float* __restrict__ out)
{
    const int gid = blockIdx.x * 256 + threadIdx.x;  // BN_*16 threads, 4 cols each
    const int bi = gid >> 4, c4 = (gid & 15) * 4;
    float4 s = make_float4(0.f, 0.f, 0.f, 0.f);
    #pragma unroll
    for (int seg = 0; seg < SEG; ++seg) {
        const float4 v = *(const float4*)(partial + ((size_t)seg * BN_ + bi) * FOUT + c4);
        s.x += v.x; s.y += v.y; s.z += v.z; s.w += v.w;
    }
    const float rs = 1.0f / s_buf[bi];
    float4 o; float x;
    x = s.x * rs; o.x = x > 0.f ? x : __expf(x) - 1.f;
    x = s.y * rs; o.y = x > 0.f ? x : __expf(x) - 1.f;
    x = s.z * rs; o.z = x > 0.f ? x : __expf(x) - 1.f;
    x = s.w * rs; o.w = x > 0.f ? x : __expf(x) - 1.f;
    *(float4*)(out + (size_t)bi * FOUT + c4) = o;
}

extern "C" void kernel_launch(void* const* d_in, const int* in_sizes, int n_in,
                              void* d_out, int out_size, void* d_ws, size_t ws_size,
                              hipStream_t stream) {
    const float* h = (const float*)d_in[0];
    const int* adj = (const int*)d_in[1];
    const float* W = (const float*)d_in[2];
    const float* a = (const float*)d_in[3];
    float* out = (float*)d_out;

    // ws layout: WhTB bf16 2MB | e_src 64KB | e_dst 64KB | s 64KB | partial SEG*4MB (~34.3MB total)
    char* ws = (char*)d_ws;
    ushort_t* WhTB = (ushort_t*)ws;
    float* e_src = (float*)(ws + 2 * 1024 * 1024);
    float* e_dst = e_src + BN_;
    float* s_buf = e_dst + BN_;
    float* partial = s_buf + BN_;

    hipMemsetAsync(s_buf, 0, BN_ * sizeof(float), stream);
    k1_proj<<<BN_ / 16, 256, 0, stream>>>(h, W, a, WhTB, e_src, e_dst);
    k3_attn<<<dim3(128, SEG), 256, 0, stream>>>(adj, WhTB, e_src, e_dst, s_buf, partial);
    k4_out<<<BN_ * 16 / 256, 256, 0, stream>>>(partial, s_buf, out);
}

// Round 2
// 270.686 us; speedup vs baseline: 1.0239x; 1.0239x over previous
//
#include <hip/hip_runtime.h>
#include <hip/hip_bf16.h>

#define B_ 8
#define N_ 2048
#define FIN 256
#define FOUT 64
#define BN_ (B_ * N_)
#define KSEG 256   // per-wave K segment; 8 waves cover N_=2048

typedef unsigned short ushort_t;
typedef __attribute__((ext_vector_type(8))) __bf16 bf16x8;
typedef __attribute__((ext_vector_type(4))) float f32x4;

union U4B8 { uint4 u; bf16x8 b; };

// ---------------- K1: Wh = h @ W ; e_src/e_dst ; WhT stored bf16 transposed ----------------
// block = 256 thr = 4 waves; each wave: 4 consecutive rows, lane = output col c.
__global__ __launch_bounds__(256) void k1_proj(
    const float* __restrict__ h, const float* __restrict__ W,
    const float* __restrict__ a, ushort_t* __restrict__ WhTB,
    float* __restrict__ e_src, float* __restrict__ e_dst)
{
    const int t = threadIdx.x;
    const int lane = t & 63;
    const int w = t >> 6;
    const int gr = blockIdx.x * 16 + w * 4;  // global row (b*N+i), 4 rows per wave
    const int c = lane;
    const float* hrow = h + (size_t)gr * FIN;
    float v0 = 0.f, v1 = 0.f, v2 = 0.f, v3 = 0.f;
    for (int k = 0; k < FIN; k += 4) {
        const float4 h0 = *(const float4*)(hrow + k);
        const float4 h1 = *(const float4*)(hrow + FIN + k);
        const float4 h2 = *(const float4*)(hrow + 2 * FIN + k);
        const float4 h3 = *(const float4*)(hrow + 3 * FIN + k);
        const float w0 = W[(k + 0) * FOUT + c];
        const float w1 = W[(k + 1) * FOUT + c];
        const float w2 = W[(k + 2) * FOUT + c];
        const float w3 = W[(k + 3) * FOUT + c];
        v0 += h0.x * w0 + h0.y * w1 + h0.z * w2 + h0.w * w3;
        v1 += h1.x * w0 + h1.y * w1 + h1.z * w2 + h1.w * w3;
        v2 += h2.x * w0 + h2.y * w1 + h2.z * w2 + h2.w * w3;
        v3 += h3.x * w0 + h3.y * w1 + h3.z * w2 + h3.w * w3;
    }
    // e_src/e_dst wave reductions over c
    const float a1c = a[c], a2c = a[FOUT + c];
    float s10 = v0 * a1c, s11 = v1 * a1c, s12 = v2 * a1c, s13 = v3 * a1c;
    float s20 = v0 * a2c, s21 = v1 * a2c, s22 = v2 * a2c, s23 = v3 * a2c;
    for (int off = 32; off; off >>= 1) {
        s10 += __shfl_xor(s10, off); s11 += __shfl_xor(s11, off);
        s12 += __shfl_xor(s12, off); s13 += __shfl_xor(s13, off);
        s20 += __shfl_xor(s20, off); s21 += __shfl_xor(s21, off);
        s22 += __shfl_xor(s22, off); s23 += __shfl_xor(s23, off);
    }
    if (lane == 0) {
        *(float4*)(e_src + gr) = make_float4(s10, s11, s12, s13);
        *(float4*)(e_dst + gr) = make_float4(s20, s21, s22, s23);
    }
    // WhT[b][c][i] bf16 (transposed so K3 reads K-contiguous B fragments)
    const int b = gr >> 11, i = gr & (N_ - 1);
    ushort4 us;
    us.x = __builtin_bit_cast(unsigned short, (__bf16)v0);
    us.y = __builtin_bit_cast(unsigned short, (__bf16)v1);
    us.z = __builtin_bit_cast(unsigned short, (__bf16)v2);
    us.w = __builtin_bit_cast(unsigned short, (__bf16)v3);
    *(ushort4*)(WhTB + (size_t)(b * FOUT + c) * N_ + i) = us;
}

// ---------------- K3: fused attention+PV, split-K within block ----------------
// grid = 1024 blocks of 512 thr (8 waves). Block tile = 16 rows; wave = K-segment 256.
// b = bid & 7 pins each batch to one XCD so WhTB[b] (2 MB) stays L2-resident.
// P~[i][j] = adj ? exp(leaky(e_src[i]+e_dst[j])) : 0 ; unnormalized accumulate via MFMA;
// LDS cross-wave reduce; normalize by row sum; ELU; direct store. No partials, no atomics.
__global__ __launch_bounds__(512, 4) void k3_attn(
    const int* __restrict__ adj, const ushort_t* __restrict__ WhTB,
    const float* __restrict__ e_src, const float* __restrict__ e_dst,
    float* __restrict__ out)
{
    __shared__ float red[8 * 16 * 68];   // [wid][row][68] pad: bank 2-way (free), 16B aligned
    __shared__ float sred[8 * 16];
    __shared__ float ssum[16];

    const int t = threadIdx.x;
    const int lane = t & 63, wid = t >> 6;
    const int l15 = lane & 15, g = lane >> 4;   // MFMA lane decomposition
    const int b = blockIdx.x & 7;               // XCD pin
    const int tile = blockIdx.x >> 3;
    const int i0 = tile * 16;
    const int jseg = wid * KSEG;

    const size_t row_g = (size_t)(b * N_ + i0 + l15);
    const int* arow = adj + row_g * N_ + jseg + g * 8;
    const float* edp = e_dst + b * N_ + jseg + g * 8;
    const ushort_t* wb = WhTB + (size_t)(b * FOUT + l15) * N_ + jseg + g * 8;
    const float es = e_src[row_g];

    f32x4 acc[4];
    #pragma unroll
    for (int n = 0; n < 4; ++n)
        #pragma unroll
        for (int r = 0; r < 4; ++r) acc[n][r] = 0.f;
    float srow = 0.f;

    // register double-buffer prefetch of adj (HBM-latency hiding)
    int4 c0 = *(const int4*)(arow);
    int4 c1 = *(const int4*)(arow + 4);
    #pragma unroll
    for (int kc = 0; kc < KSEG; kc += 32) {
        int4 p0, p1;
        if (kc + 32 < KSEG) {
            p0 = *(const int4*)(arow + kc + 32);
            p1 = *(const int4*)(arow + kc + 36);
        } else { p0 = c0; p1 = c1; }
        const float4 ed0 = *(const float4*)(edp + kc);
        const float4 ed1 = *(const float4*)(edp + kc + 4);
        const float ev[8] = {ed0.x, ed0.y, ed0.z, ed0.w, ed1.x, ed1.y, ed1.z, ed1.w};
        const int aa[8] = {c0.x, c0.y, c0.z, c0.w, c1.x, c1.y, c1.z, c1.w};
        bf16x8 af;
        #pragma unroll
        for (int u = 0; u < 8; ++u) {
            float e = es + ev[u];
            e = fmaxf(e, 0.2f * e);            // leaky_relu
            const float p = aa[u] > 0 ? __expf(e) : 0.f;
            srow += p;
            af[u] = (__bf16)p;
        }
        #pragma unroll
        for (int n = 0; n < 4; ++n) {
            U4B8 bfr;
            bfr.u = *(const uint4*)(wb + (size_t)n * 16 * N_ + kc);
            acc[n] = __builtin_amdgcn_mfma_f32_16x16x32_bf16(af, bfr.b, acc[n], 0, 0, 0);
        }
        c0 = p0; c1 = p1;
    }

    // per-row partial sums: lane holds k-subset of row l15 -> reduce over g
    srow += __shfl_xor(srow, 16);
    srow += __shfl_xor(srow, 32);
    if (lane < 16) sred[wid * 16 + lane] = srow;

    // C layout: col = n*16 + l15, row = g*4 + r
    #pragma unroll
    for (int n = 0; n < 4; ++n)
        #pragma unroll
        for (int r = 0; r < 4; ++r)
            red[(wid * 16 + g * 4 + r) * 68 + n * 16 + l15] = acc[n][r];
    __syncthreads();

    if (t < 16) {
        float s = 0.f;
        #pragma unroll
        for (int w = 0; w < 8; ++w) s += sred[w * 16 + t];
        ssum[t] = 1.0f / s;
    }
    const int row = t >> 4, c4 = (t & 15) * 4;
    float4 v = make_float4(0.f, 0.f, 0.f, 0.f);
    if (t < 256) {
        #pragma unroll
        for (int w = 0; w < 8; ++w) {
            const float4 u = *(const float4*)&red[(w * 16 + row) * 68 + c4];
            v.x += u.x; v.y += u.y; v.z += u.z; v.w += u.w;
        }
    }
    __syncthreads();
    if (t < 256) {
        const float rs = ssum[row];
        float4 o; float x;
        x = v.x * rs; o.x = x > 0.f ? x : __expf(x) - 1.f;
        x = v.y * rs; o.y = x > 0.f ? x : __expf(x) - 1.f;
        x = v.z * rs; o.z = x > 0.f ? x : __expf(x) - 1.f;
        x = v.w * rs; o.w = x > 0.f ? x : __expf(x) - 1.f;
        *(float4*)(out + ((size_t)(b * N_ + i0 + row)) * FOUT + c4) = o;
    }
}

extern "C" void kernel_launch(void* const* d_in, const int* in_sizes, int n_in,
                              void* d_out, int out_size, void* d_ws, size_t ws_size,
                              hipStream_t stream) {
    const float* h = (const float*)d_in[0];
    const int* adj = (const int*)d_in[1];
    const float* W = (const float*)d_in[2];
    const float* a = (const float*)d_in[3];
    float* out = (float*)d_out;

    // ws layout: WhTB bf16 2MB | e_src 64KB | e_dst 64KB
    char* ws = (char*)d_ws;
    ushort_t* WhTB = (ushort_t*)ws;
    float* e_src = (float*)(ws + 2 * 1024 * 1024);
    float* e_dst = e_src + BN_;

    k1_proj<<<BN_ / 16, 256, 0, stream>>>(h, W, a, WhTB, e_src, e_dst);
    k3_attn<<<BN_ / 16, 512, 0, stream>>>(adj, WhTB, e_src, e_dst, out);
}